// Round 3
// baseline (47.057 us; speedup 1.0000x reference)
//
#include <hip/hip_runtime.h>
#include <math.h>

#define LOG2E 1.4426950408889634f
// s[i,j] = Ci + Dj + sum_h ab_h*|hq_ih + hkb_jh|,  ab = 0.05*a, Dj = 0.075*(a.hkb_j)
// Ci is constant per row -> cancels in softmax -> dropped.

// ---------------- Kernel A: hq = qs@(Wq+Wd); hkbT[b][h][j] = ks@(Wk-Wd)+bias; Dj; abd
__global__ __launch_bounds__(256) void prep_kernel(
    const float* __restrict__ qs, const float* __restrict__ ks,
    const float* __restrict__ W, const float* __restrict__ bias,
    const float* __restrict__ a,
    float* __restrict__ hq, float* __restrict__ hkbT,
    float* __restrict__ Dj, float* __restrict__ abd) {
  __shared__ __align__(16) float wcomb[64][68];
  __shared__ __align__(16) float xin[64][68];
  const int blk = blockIdx.x;
  const bool qpart = blk < 64;
  const int r0 = (qpart ? blk : blk - 64) * 64;
  const int t = threadIdx.x;
  const float* src = qpart ? qs : ks;
  if (blk == 0 && t < 64) abd[t] = 0.05f * a[t];
  for (int rep = 0; rep < 16; ++rep) {
    int e = rep * 256 + t;
    int row = e >> 6, col = e & 63;
    float wd = W[(128 + row) * 64 + col];
    float wm = qpart ? (W[row * 64 + col] + wd)
                     : (W[(64 + row) * 64 + col] - wd);
    wcomb[row][col] = wm;
    xin[row][col] = src[(r0 + row) * 64 + col];
  }
  __syncthreads();
  const int r = t >> 2;
  const int h0 = (t & 3) << 4;
  float acc[16];
#pragma unroll
  for (int k = 0; k < 16; ++k) acc[k] = 0.f;
#pragma unroll 8
  for (int d = 0; d < 64; ++d) {
    float xv = xin[r][d];
#pragma unroll
    for (int c = 0; c < 4; ++c) {
      float4 w4 = *(const float4*)&wcomb[d][h0 + (c << 2)];
      acc[c * 4 + 0] = fmaf(xv, w4.x, acc[c * 4 + 0]);
      acc[c * 4 + 1] = fmaf(xv, w4.y, acc[c * 4 + 1]);
      acc[c * 4 + 2] = fmaf(xv, w4.z, acc[c * 4 + 2]);
      acc[c * 4 + 3] = fmaf(xv, w4.w, acc[c * 4 + 3]);
    }
  }
  int grow = r0 + r;
  if (qpart) {
#pragma unroll
    for (int c = 0; c < 4; ++c) {
      float4 o;
      o.x = acc[c * 4 + 0]; o.y = acc[c * 4 + 1];
      o.z = acc[c * 4 + 2]; o.w = acc[c * 4 + 3];
      *(float4*)&hq[grow * 64 + h0 + (c << 2)] = o;
    }
  } else {
    int bidx = grow >> 10;
    int j = grow & 1023;
    float part = 0.f;
#pragma unroll
    for (int k = 0; k < 16; ++k) {
      float v = acc[k] + bias[h0 + k];
      hkbT[(bidx * 64 + h0 + k) * 1024 + j] = v;
      part += a[h0 + k] * v;
    }
    part += __shfl_xor(part, 1);
    part += __shfl_xor(part, 2);
    if ((t & 3) == 0) Dj[bidx * 1024 + j] = 0.075f * part;
  }
}

// ---------------- Kernel B: 8 rows x 512 j per block; partial flash softmax ----
__global__ __launch_bounds__(256, 4) void attn3_kernel(
    const float* __restrict__ vs,
    const float* __restrict__ hq, const float* __restrict__ hkbT,
    const float* __restrict__ Dj, const float* __restrict__ abd,
    float* __restrict__ out0, float* __restrict__ opart1,
    float* __restrict__ mpart, float* __restrict__ lpart) {
  __shared__ __align__(16) float plds[8][512];  // p[r][jloc]; reused as obuf
  __shared__ float redm[8][4];
  __shared__ float redl[8][4];
  const int t = threadIdx.x;
  const int lane = t & 63;
  const int w = t >> 6;
  const int b = blockIdx.y;
  const int rowbase = blockIdx.x * 8;
  const int hz = blockIdx.z;
  const int growbase = b * 1024 + rowbase;

  const float* hq_b = hq + growbase * 64;
  const float* hkbT_b = hkbT + b * 64 * 1024 + hz * 512;
  const float* v_b = vs + (b * 1024 + hz * 512) * 64;

  const int jloc = w * 128 + lane * 2;
  float2 d2 = *(const float2*)(Dj + b * 1024 + hz * 512 + jloc);

  float s[8][2];
#pragma unroll
  for (int r = 0; r < 8; ++r) { s[r][0] = 0.f; s[r][1] = 0.f; }

  // ---- scores: s[r][c] += ab_h * |q[r][h] + k[h][jloc+c]|  (q, ab in SGPRs) ----
#pragma unroll
  for (int slab = 0; slab < 16; ++slab) {
    const int h0 = slab * 4;
    float2 k2[4];
#pragma unroll
    for (int hh = 0; hh < 4; ++hh)
      k2[hh] = *(const float2*)(hkbT_b + (h0 + hh) * 1024 + jloc);
#pragma unroll
    for (int r = 0; r < 8; ++r) {
#pragma unroll
      for (int hh = 0; hh < 4; ++hh) {
        const float qv = hq_b[r * 64 + h0 + hh];  // wave-uniform -> s_load
        const float ab = abd[h0 + hh];            // wave-uniform -> s_load
        float x0, x1;
        asm("v_add_f32 %0, %1, %2" : "=v"(x0) : "s"(qv), "v"(k2[hh].x));
        asm("v_fma_f32 %0, %1, |%2|, %0" : "+v"(s[r][0]) : "s"(ab), "v"(x0));
        asm("v_add_f32 %0, %1, %2" : "=v"(x1) : "s"(qv), "v"(k2[hh].y));
        asm("v_fma_f32 %0, %1, |%2|, %0" : "+v"(s[r][1]) : "s"(ab), "v"(x1));
      }
    }
  }
#pragma unroll
  for (int r = 0; r < 8; ++r) { s[r][0] += d2.x; s[r][1] += d2.y; }

  // ---- partial softmax over this block's 512 j ----
#pragma unroll
  for (int r = 0; r < 8; ++r) {
    float m = fmaxf(s[r][0], s[r][1]);
#pragma unroll
    for (int off = 32; off >= 1; off >>= 1) m = fmaxf(m, __shfl_xor(m, off));
    if (lane == 0) redm[r][w] = m;
  }
  __syncthreads();
  float mx[8], lt[8];
#pragma unroll
  for (int r = 0; r < 8; ++r) {
    float4 rm = *(const float4*)&redm[r][0];
    mx[r] = fmaxf(fmaxf(rm.x, rm.y), fmaxf(rm.z, rm.w));
  }
#pragma unroll
  for (int r = 0; r < 8; ++r) {
    float p0 = __builtin_amdgcn_exp2f((s[r][0] - mx[r]) * LOG2E);
    float p1 = __builtin_amdgcn_exp2f((s[r][1] - mx[r]) * LOG2E);
    float2 pw; pw.x = p0; pw.y = p1;
    *(float2*)&plds[r][jloc] = pw;
    float ps = p0 + p1;
#pragma unroll
    for (int off = 32; off >= 1; off >>= 1) ps += __shfl_xor(ps, off);
    if (lane == 0) redl[r][w] = ps;
  }
  __syncthreads();
#pragma unroll
  for (int r = 0; r < 8; ++r) {
    float4 rl = *(const float4*)&redl[r][0];
    lt[r] = (rl.x + rl.y) + (rl.z + rl.w);
  }
#pragma unroll
  for (int r = 0; r < 8; ++r) {
    if (t == r) {
      mpart[hz * 4096 + growbase + r] = mx[r];
      lpart[hz * 4096 + growbase + r] = lt[r];
    }
  }

  // ---- PV over this wave's own 128-j chunk (p via LDS transpose) ----
  const int jsub = lane >> 4;
  const int dq = (lane & 15) * 4;
  const int cbase = w * 128;
  float o[8][4];
#pragma unroll
  for (int r = 0; r < 8; ++r)
#pragma unroll
    for (int dd = 0; dd < 4; ++dd) o[r][dd] = 0.f;

#pragma unroll
  for (int step = 0; step < 8; ++step) {
    int j = cbase + step * 16 + jsub * 4;
    float4 v0 = *(const float4*)(v_b + (j + 0) * 64 + dq);
    float4 v1 = *(const float4*)(v_b + (j + 1) * 64 + dq);
    float4 v2 = *(const float4*)(v_b + (j + 2) * 64 + dq);
    float4 v3 = *(const float4*)(v_b + (j + 3) * 64 + dq);
#pragma unroll
    for (int r = 0; r < 8; ++r) {
      float4 p4 = *(const float4*)&plds[r][j];
      o[r][0] = fmaf(p4.x, v0.x, o[r][0]); o[r][1] = fmaf(p4.x, v0.y, o[r][1]);
      o[r][2] = fmaf(p4.x, v0.z, o[r][2]); o[r][3] = fmaf(p4.x, v0.w, o[r][3]);
      o[r][0] = fmaf(p4.y, v1.x, o[r][0]); o[r][1] = fmaf(p4.y, v1.y, o[r][1]);
      o[r][2] = fmaf(p4.y, v1.z, o[r][2]); o[r][3] = fmaf(p4.y, v1.w, o[r][3]);
      o[r][0] = fmaf(p4.z, v2.x, o[r][0]); o[r][1] = fmaf(p4.z, v2.y, o[r][1]);
      o[r][2] = fmaf(p4.z, v2.z, o[r][2]); o[r][3] = fmaf(p4.z, v2.w, o[r][3]);
      o[r][0] = fmaf(p4.w, v3.x, o[r][0]); o[r][1] = fmaf(p4.w, v3.y, o[r][1]);
      o[r][2] = fmaf(p4.w, v3.z, o[r][2]); o[r][3] = fmaf(p4.w, v3.w, o[r][3]);
    }
  }
  __syncthreads();  // all p reads done before obuf reuse

#pragma unroll
  for (int r = 0; r < 8; ++r)
#pragma unroll
    for (int dd = 0; dd < 4; ++dd) {
      o[r][dd] += __shfl_xor(o[r][dd], 16);
      o[r][dd] += __shfl_xor(o[r][dd], 32);
    }
  float* ob = &plds[0][0];  // [4w][8r][64d] = 8KB
  if (lane < 16) {
#pragma unroll
    for (int r = 0; r < 8; ++r) {
      float4 ov; ov.x = o[r][0]; ov.y = o[r][1]; ov.z = o[r][2]; ov.w = o[r][3];
      *(float4*)&ob[(w * 8 + r) * 64 + dq] = ov;
    }
  }
  __syncthreads();
  {
    int e = t * 2;
    int r = e >> 6, d = e & 63;
    float ax = 0.f, ay = 0.f;
#pragma unroll
    for (int wv = 0; wv < 4; ++wv) {
      float2 pv = *(const float2*)&ob[(wv * 8 + r) * 64 + d];
      ax += pv.x; ay += pv.y;
    }
    float* obase = (hz == 0) ? out0 : opart1;
    float2 res; res.x = ax; res.y = ay;  // unnormalized partial
    *(float2*)&obase[(growbase + r) * 64 + d] = res;
  }
}

// ---------------- Kernel C: combine the two j-halves, normalize in place ------
__global__ __launch_bounds__(256) void combine_kernel(
    const float* __restrict__ opart1, const float* __restrict__ mpart,
    const float* __restrict__ lpart, float* __restrict__ out) {
  int idx = blockIdx.x * 256 + threadIdx.x;
  int e = idx * 2;
  int row = e >> 6;
  float m0 = mpart[row], m1 = mpart[4096 + row];
  float l0 = lpart[row], l1 = lpart[4096 + row];
  float M = fmaxf(m0, m1);
  float w0 = __builtin_amdgcn_exp2f((m0 - M) * LOG2E);
  float w1 = __builtin_amdgcn_exp2f((m1 - M) * LOG2E);
  float inv = 1.f / (l0 * w0 + l1 * w1);
  float2 o0 = *(const float2*)&out[e];
  float2 o1 = *(const float2*)&opart1[e];
  float2 res;
  res.x = (o0.x * w0 + o1.x * w1) * inv;
  res.y = (o0.y * w0 + o1.y * w1) * inv;
  *(float2*)&out[e] = res;
}

extern "C" void kernel_launch(void* const* d_in, const int* in_sizes, int n_in,
                              void* d_out, int out_size, void* d_ws, size_t ws_size,
                              hipStream_t stream) {
  const float* qs = (const float*)d_in[0];
  const float* ks = (const float*)d_in[1];
  const float* vs = (const float*)d_in[2];
  const float* W  = (const float*)d_in[3];
  const float* bi = (const float*)d_in[4];
  const float* a  = (const float*)d_in[5];
  float* out = (float*)d_out;
  float* hq     = (float*)d_ws;             // 1MB
  float* hkbT   = hq + 262144;              // 1MB
  float* Dj     = hkbT + 262144;            // 16KB
  float* abd    = Dj + 4096;                // 256B
  float* opart1 = abd + 64;                 // 1MB
  float* mpart  = opart1 + 262144;          // 32KB
  float* lpart  = mpart + 8192;             // 32KB
  prep_kernel<<<128, 256, 0, stream>>>(qs, ks, W, bi, a, hq, hkbT, Dj, abd);
  attn3_kernel<<<dim3(128, 4, 2), 256, 0, stream>>>(vs, hq, hkbT, Dj, abd,
                                                    out, opart1, mpart, lpart);
  combine_kernel<<<512, 256, 0, stream>>>(opart1, mpart, lpart, out);
}